// Round 1
// baseline (243.621 us; speedup 1.0000x reference)
//
#include <hip/hip_runtime.h>
#include <hip/hip_bf16.h>

// Problem constants: B=4, S=4096, D=1024, T=16, TD=64, K=4
typedef float floatx4 __attribute__((ext_vector_type(4)));
typedef __bf16 bf16x8 __attribute__((ext_vector_type(8)));

__device__ __forceinline__ unsigned short f2bf(float f){
  unsigned u = __builtin_bit_cast(unsigned, f);
  u += 0x7fffu + ((u >> 16) & 1u);
  return (unsigned short)(u >> 16);
}
__device__ __forceinline__ unsigned pk2(float a, float b){
  return (unsigned)f2bf(a) | ((unsigned)f2bf(b) << 16);
}
__device__ __forceinline__ float wred64(float v){
  v += __shfl_xor(v, 32); v += __shfl_xor(v, 16); v += __shfl_xor(v, 8);
  v += __shfl_xor(v, 4);  v += __shfl_xor(v, 2);  v += __shfl_xor(v, 1);
  return v;
}
__device__ __forceinline__ float gelu_f(float v){
  return 0.5f * v * (1.0f + erff(v * 0.7071067811865476f));
}

// ---------------- K1: LN + per-block tile-sum partials (deterministic) ----------------
__global__ __launch_bounds__(256) void wk_ln_part(const float* __restrict__ x,
    const float* __restrict__ gm, const float* __restrict__ bt, float* __restrict__ part){
  __shared__ float red[4][1024];
  const int tid = threadIdx.x, w = tid >> 6, lane = tid & 63;
  const int blk = blockIdx.x;
  floatx4 gv[4], bv[4];
#pragma unroll
  for (int j = 0; j < 4; ++j){
    gv[j] = *(const floatx4*)(gm + j*256 + lane*4);
    bv[j] = *(const floatx4*)(bt + j*256 + lane*4);
  }
  floatx4 acc[4];
#pragma unroll
  for (int j = 0; j < 4; ++j){ acc[j][0]=0.f; acc[j][1]=0.f; acc[j][2]=0.f; acc[j][3]=0.f; }
  const int row0 = blk*32 + w*8;
#pragma unroll 2
  for (int r = 0; r < 8; ++r){
    const float* xr = x + (size_t)(row0 + r) * 1024;
    floatx4 xv[4];
#pragma unroll
    for (int j = 0; j < 4; ++j) xv[j] = *(const floatx4*)(xr + j*256 + lane*4);
    float s = 0.f, s2 = 0.f;
#pragma unroll
    for (int j = 0; j < 4; ++j)
#pragma unroll
      for (int e = 0; e < 4; ++e){ float v = xv[j][e]; s += v; s2 += v*v; }
    s = wred64(s); s2 = wred64(s2);
    const float mu = s * (1.0f/1024.0f);
    const float rs = rsqrtf(s2 * (1.0f/1024.0f) - mu*mu + 1e-5f);
#pragma unroll
    for (int j = 0; j < 4; ++j)
#pragma unroll
      for (int e = 0; e < 4; ++e)
        acc[j][e] += (xv[j][e] - mu) * rs * gv[j][e] + bv[j][e];
  }
#pragma unroll
  for (int j = 0; j < 4; ++j) *(floatx4*)(&red[w][j*256 + lane*4]) = acc[j];
  __syncthreads();
  const int p = tid * 4;
  floatx4 s0 = *(const floatx4*)(&red[0][p]);
  floatx4 s1 = *(const floatx4*)(&red[1][p]);
  floatx4 s2v = *(const floatx4*)(&red[2][p]);
  floatx4 s3 = *(const floatx4*)(&red[3][p]);
  *(floatx4*)(part + (size_t)blk*1024 + p) = s0 + s1 + s2v + s3;
}

// ---------------- K2a: reduce partials -> tile_repr; convert W1/W2 to bf16 ----------------
__global__ __launch_bounds__(256) void wk_reduce(const float* __restrict__ part, float* __restrict__ trep,
    const float* __restrict__ W1, const float* __restrict__ W2,
    unsigned short* __restrict__ W1bf, unsigned short* __restrict__ W2bf){
  __shared__ float red[4][64];
  const int j = blockIdx.x, b = j >> 4, chunk = j & 15;
  const int t = threadIdx.x, po = t & 63, part4 = t >> 6;
  const int p = chunk*64 + po;
  float s = 0.f;
  for (int i = 0; i < 32; ++i) s += part[(size_t)(b*128 + part4*32 + i)*1024 + p];
  red[part4][po] = s;
  __syncthreads();
  if (t < 64) trep[b*1024 + chunk*64 + t] = red[0][t] + red[1][t] + red[2][t] + red[3][t];
  for (int i = j*256 + t; i < 128*320; i += 64*256) W1bf[i] = f2bf(W1[i]);
  for (int i = j*256 + t; i < 64*128;  i += 64*256) W2bf[i] = f2bf(W2[i]);
}

// ---------------- K2b: routing (q/k linears, l2norm, scores, stable top-4) ----------------
__global__ __launch_bounds__(256) void wk_route(const float* __restrict__ trep,
    const float* __restrict__ Wq, const float* __restrict__ bq,
    const float* __restrict__ Wk, const float* __restrict__ bk, int* __restrict__ routes){
  __shared__ float tr[4096];
  __shared__ float qn[4096], kn[4096];
  __shared__ float redq[64][4], redk[64][4];
  const int t = threadIdx.x;
  for (int i = t; i < 4096; i += 256) tr[i] = trep[i] * (1.0f/4096.0f);
  __syncthreads();
  const int pair = t >> 2, part = t & 3;
  const float* trp = tr + pair*64;
  float qv[16], kv[16];
  float sq = 0.f, sk = 0.f;
  for (int dd = 0; dd < 16; ++dd){
    const int d = part*16 + dd;
    float aq = bq[d], ak = bk[d];
    const float* wqr = Wq + d*64;
    const float* wkr = Wk + d*64;
    for (int d2 = 0; d2 < 64; ++d2){ float v = trp[d2]; aq += wqr[d2]*v; ak += wkr[d2]*v; }
    qv[dd] = aq; kv[dd] = ak; sq += aq*aq; sk += ak*ak;
  }
  redq[pair][part] = sq; redk[pair][part] = sk;
  __syncthreads();
  const float nq = sqrtf(redq[pair][0]+redq[pair][1]+redq[pair][2]+redq[pair][3]);
  const float nk = sqrtf(redk[pair][0]+redk[pair][1]+redk[pair][2]+redk[pair][3]);
  const float iq = 1.0f / fmaxf(nq, 1e-12f), ik = 1.0f / fmaxf(nk, 1e-12f);
  for (int dd = 0; dd < 16; ++dd){
    qn[pair*64 + part*16 + dd] = qv[dd]*iq;
    kn[pair*64 + part*16 + dd] = kv[dd]*ik;
  }
  __syncthreads();
  if (t < 64){
    const int b = t >> 4, tt = t & 15;
    const float* qp = qn + t*64;
    float sc[16];
    for (int u = 0; u < 16; ++u){
      const float* kp = kn + (b*16 + u)*64;
      float s = 0.f;
      for (int d2 = 0; d2 < 64; ++d2) s += qp[d2]*kp[d2];
      sc[u] = s;
    }
    sc[tt] = -3.0e38f;
    for (int kk = 0; kk < 4; ++kk){
      float best = -3.4e38f; int bi = 0;
      for (int u = 0; u < 16; ++u) if (sc[u] > best){ best = sc[u]; bi = u; }
      routes[t*4 + kk] = bi;
      sc[bi] = -3.4e38f;
    }
  }
}

// ---------------- K3: fused LN + wormhole-MLP + residual ----------------
#define MFMA16(accv, av, bbv) accv = __builtin_amdgcn_mfma_f32_16x16x32_bf16(av, bbv, accv, 0, 0, 0)

__global__ __launch_bounds__(256, 1) void wk_main(const float* __restrict__ x,
    const float* __restrict__ gm, const float* __restrict__ bt,
    const float* __restrict__ b1, const float* __restrict__ b2p,
    const unsigned short* __restrict__ W1bf, const unsigned short* __restrict__ W2bf,
    const int* __restrict__ routes, float* __restrict__ out){
  extern __shared__ char sm[];
  const int tid = threadIdx.x, w = tid >> 6, lane = tid & 63;
  const int c = lane & 15, g = lane >> 4;
  // stage W1 swizzled: row h (640B), byte k ^ ((h&7)<<4)
  {
    const int h = tid >> 1, half = tid & 1;
    const unsigned short* src = W1bf + h*320 + half*160;
    char* dstrow = sm + h*640;
    const int sw = (h & 7) << 4;
#pragma unroll
    for (int jj = 0; jj < 20; ++jj){
      const int k16 = half*20 + jj;
      *(int4*)(dstrow + ((k16*16) ^ sw)) = *(const int4*)(src + jj*8);
    }
#pragma unroll
    for (int q = 0; q < 4; ++q){
      const int cid = tid*4 + q, row = cid >> 4, k16 = cid & 15;
      *(int4*)(sm + 81920 + row*256 + ((k16*16) ^ ((row & 7) << 4))) = *(const int4*)(W2bf + row*128 + k16*8);
    }
  }
  const int wid = blockIdx.x*4 + w;      // 0..1023
  const int row_base = wid * 16;         // 16 rows per wave
  const int b = row_base >> 12;
  float gv[16], bv[16];
#pragma unroll
  for (int k = 0; k < 16; ++k){
    const int p = g*256 + (k >> 2)*64 + (k & 3)*16 + c;
    gv[k] = gm[p]; bv[k] = bt[p];
  }
  floatx4 b1v[8];
#pragma unroll
  for (int mm = 0; mm < 8; ++mm) b1v[mm] = *(const floatx4*)(b1 + mm*16 + g*4);
  float b2v[4];
#pragma unroll
  for (int nn = 0; nn < 4; ++nn) b2v[nn] = b2p[nn*16 + c];
  const int4 rt4 = *(const int4*)(routes + (b*16 + c)*4);
  const int rts[5] = {c, rt4.x, rt4.y, rt4.z, rt4.w};
  char* xnb = sm + 98304 + w*12288;      // 4 rows x 2048B swizzled bf16 xn
  char* Hb  = xnb + 8192;                // 16x128 bf16 H, swizzled
  const int swc = (c & 7) << 4;
  const int g16 = g * 16;
  const int cw1 = c * 640;
  __syncthreads();

  float xa[64], xbuf[64];

#define LOADP(DST, PASS) { \
  const float* bp_ = x + (size_t)(row_base + (PASS)*4)*1024 + g*256 + c; \
  _Pragma("unroll") for (int r_ = 0; r_ < 4; ++r_) \
  _Pragma("unroll") for (int k_ = 0; k_ < 16; ++k_) \
    DST[r_*16 + k_] = bp_[(size_t)r_*1024 + (k_ >> 2)*64 + (k_ & 3)*16]; }

#define PASSBODY(PASS, XC, XN, DOPREF) { \
  if (DOPREF) LOADP(XN, (PASS)+1) \
  _Pragma("unroll") for (int r_ = 0; r_ < 4; ++r_){ \
    float s_ = 0.f, s2_ = 0.f; \
    _Pragma("unroll") for (int k_ = 0; k_ < 16; ++k_){ float v_ = XC[r_*16+k_]; s_ += v_; s2_ += v_*v_; } \
    s_ = wred64(s_); s2_ = wred64(s2_); \
    const float mu_ = s_ * (1.0f/1024.0f); \
    const float rs_ = rsqrtf(s2_ * (1.0f/1024.0f) - mu_*mu_ + 1e-5f); \
    _Pragma("unroll") for (int k_ = 0; k_ < 16; ++k_){ \
      const float xnv_ = (XC[r_*16+k_] - mu_) * rs_ * gv[k_] + bv[k_]; \
      const int reg_ = k_ >> 2, nn_ = k_ & 3; \
      const int t_ = g*4 + reg_; \
      *(unsigned short*)(xnb + r_*2048 + t_*128 + (((nn_*32) + c*2) ^ ((t_ & 7) << 4))) = f2bf(xnv_); \
    } \
  } \
  floatx4 acc[4][8]; \
  _Pragma("unroll") for (int r_ = 0; r_ < 4; ++r_) \
  _Pragma("unroll") for (int m_ = 0; m_ < 8; ++m_){ acc[r_][m_][0]=0.f; acc[r_][m_][1]=0.f; acc[r_][m_][2]=0.f; acc[r_][m_][3]=0.f; } \
  _Pragma("unroll") for (int kk_ = 0; kk_ < 10; ++kk_){ \
    const int s_ = rts[kk_ >> 1]; \
    const int baddr_ = s_*128 + ((((kk_ & 1)*64) + g16) ^ ((s_ & 7) << 4)); \
    bf16x8 bfr_[4]; \
    _Pragma("unroll") for (int r_ = 0; r_ < 4; ++r_) bfr_[r_] = *(const bf16x8*)(xnb + r_*2048 + baddr_); \
    const int koffw_ = ((kk_*64) + g16) ^ swc; \
    bf16x8 af_[8]; \
    _Pragma("unroll") for (int m_ = 0; m_ < 8; ++m_) af_[m_] = *(const bf16x8*)(sm + cw1 + m_*10240 + koffw_); \
    _Pragma("unroll") for (int r_ = 0; r_ < 4; ++r_) \
    _Pragma("unroll") for (int m_ = 0; m_ < 8; ++m_) \
      MFMA16(acc[r_][m_], af_[m_], bfr_[r_]); \
  } \
  _Pragma("unroll") for (int r_ = 0; r_ < 4; ++r_){ \
    _Pragma("unroll") for (int m_ = 0; m_ < 8; ++m_){ \
      floatx4 z_ = acc[r_][m_] + b1v[m_]; \
      uint2 pv_; \
      pv_.x = pk2(gelu_f(z_[0]), gelu_f(z_[1])); \
      pv_.y = pk2(gelu_f(z_[2]), gelu_f(z_[3])); \
      *(uint2*)(Hb + c*256 + (((m_*32) + g*8) ^ swc)) = pv_; \
    } \
    floatx4 a2c[4]; \
    _Pragma("unroll") for (int n_ = 0; n_ < 4; ++n_){ a2c[n_][0]=0.f; a2c[n_][1]=0.f; a2c[n_][2]=0.f; a2c[n_][3]=0.f; } \
    _Pragma("unroll") for (int k2_ = 0; k2_ < 4; ++k2_){ \
      const bf16x8 a2_ = *(const bf16x8*)(Hb + c*256 + (((k2_*64) + g16) ^ swc)); \
      _Pragma("unroll") for (int n_ = 0; n_ < 4; ++n_){ \
        const bf16x8 b2_ = *(const bf16x8*)(sm + 81920 + (n_*16 + c)*256 + (((k2_*64) + g16) ^ swc)); \
        MFMA16(a2c[n_], a2_, b2_); \
      } \
    } \
    float* op_ = out + (size_t)(row_base + (PASS)*4 + r_)*1024 + g*256 + c; \
    _Pragma("unroll") for (int n_ = 0; n_ < 4; ++n_) \
    _Pragma("unroll") for (int reg_ = 0; reg_ < 4; ++reg_) \
      op_[reg_*64 + n_*16] = a2c[n_][reg_] + b2v[n_] + XC[r_*16 + reg_*4 + n_]; \
  } }

  LOADP(xa, 0)
  for (int pp = 0; pp < 2; ++pp){
    const int p0 = 2*pp;
    PASSBODY(p0,     xa,   xbuf, true)
    PASSBODY(p0 + 1, xbuf, xa,   (pp == 0))
  }
#undef PASSBODY
#undef LOADP
}

extern "C" void kernel_launch(void* const* d_in, const int* in_sizes, int n_in,
                              void* d_out, int out_size, void* d_ws, size_t ws_size,
                              hipStream_t stream){
  const float* x  = (const float*)d_in[0];
  const float* gm = (const float*)d_in[1];
  const float* bt = (const float*)d_in[2];
  const float* Wq = (const float*)d_in[3];
  const float* bq = (const float*)d_in[4];
  const float* Wk = (const float*)d_in[5];
  const float* bk = (const float*)d_in[6];
  const float* W1 = (const float*)d_in[7];
  const float* b1 = (const float*)d_in[8];
  const float* W2 = (const float*)d_in[9];
  const float* b2 = (const float*)d_in[10];
  float* out = (float*)d_out;
  char* ws = (char*)d_ws;
  float* part = (float*)ws;                         // 512*1024 f32 = 2MB
  float* trep = part + 512*1024;                    // 4096 f32
  int*   routes = (int*)(trep + 4096);              // 256 i32
  unsigned short* W1bf = (unsigned short*)(ws + 2114560);  // 40960 bf16
  unsigned short* W2bf = (unsigned short*)(ws + 2196480);  // 8192 bf16

  hipFuncSetAttribute((const void*)wk_main, hipFuncAttributeMaxDynamicSharedMemorySize, 147456);

  wk_ln_part<<<512, 256, 0, stream>>>(x, gm, bt, part);
  wk_reduce<<<64, 256, 0, stream>>>(part, trep, W1, W2, W1bf, W2bf);
  wk_route<<<1, 256, 0, stream>>>(trep, Wq, bq, Wk, bk, routes);
  wk_main<<<256, 256, 147456, stream>>>(x, gm, bt, b1, b2, W1bf, W2bf, routes, out);
}

// Round 2
// 142.335 us; speedup vs baseline: 1.7116x; 1.7116x over previous
//
#include <hip/hip_runtime.h>
#include <hip/hip_bf16.h>

// Problem constants: B=4, S=4096, D=1024, T=16, TD=64, K=4
typedef float floatx4 __attribute__((ext_vector_type(4)));
typedef __bf16 bf16x8 __attribute__((ext_vector_type(8)));

__device__ __forceinline__ unsigned short f2bf(float f){
  unsigned u = __builtin_bit_cast(unsigned, f);
  u += 0x7fffu + ((u >> 16) & 1u);
  return (unsigned short)(u >> 16);
}
__device__ __forceinline__ unsigned pk2(float a, float b){
  return (unsigned)f2bf(a) | ((unsigned)f2bf(b) << 16);
}
__device__ __forceinline__ float wred64(float v){
  v += __shfl_xor(v, 32); v += __shfl_xor(v, 16); v += __shfl_xor(v, 8);
  v += __shfl_xor(v, 4);  v += __shfl_xor(v, 2);  v += __shfl_xor(v, 1);
  return v;
}
// tanh-form GELU via hardware exp2/rcp (|err| vs exact-erf < 1e-3, threshold 0.142)
__device__ __forceinline__ float gelu_f(float v){
  float u = v * v;
  float y = v * __builtin_fmaf(u, 0.0356774081f, 0.7978845608f);
  float a = __builtin_fabsf(y);
  float t = __builtin_amdgcn_exp2f(-2.8853900818f * a);   // e^{-2|y|}
  float th = (1.0f - t) * __builtin_amdgcn_rcpf(1.0f + t);
  return 0.5f * (v + __builtin_fabsf(v) * th);
}

// ---------------- K1: LN + per-block tile-sum partials (deterministic) ----------------
__global__ __launch_bounds__(256) void wk_ln_part(const float* __restrict__ x,
    const float* __restrict__ gm, const float* __restrict__ bt, float* __restrict__ part){
  __shared__ float red[4][1024];
  const int tid = threadIdx.x, w = tid >> 6, lane = tid & 63;
  const int blk = blockIdx.x;
  floatx4 gv[4], bv[4];
#pragma unroll
  for (int j = 0; j < 4; ++j){
    gv[j] = *(const floatx4*)(gm + j*256 + lane*4);
    bv[j] = *(const floatx4*)(bt + j*256 + lane*4);
  }
  floatx4 acc[4];
#pragma unroll
  for (int j = 0; j < 4; ++j){ acc[j][0]=0.f; acc[j][1]=0.f; acc[j][2]=0.f; acc[j][3]=0.f; }
  const int row0 = blk*32 + w*8;
#pragma unroll 2
  for (int r = 0; r < 8; ++r){
    const float* xr = x + (size_t)(row0 + r) * 1024;
    floatx4 xv[4];
#pragma unroll
    for (int j = 0; j < 4; ++j) xv[j] = *(const floatx4*)(xr + j*256 + lane*4);
    float s = 0.f, s2 = 0.f;
#pragma unroll
    for (int j = 0; j < 4; ++j)
#pragma unroll
      for (int e = 0; e < 4; ++e){ float v = xv[j][e]; s += v; s2 += v*v; }
    s = wred64(s); s2 = wred64(s2);
    const float mu = s * (1.0f/1024.0f);
    const float rs = rsqrtf(s2 * (1.0f/1024.0f) - mu*mu + 1e-5f);
#pragma unroll
    for (int j = 0; j < 4; ++j)
#pragma unroll
      for (int e = 0; e < 4; ++e)
        acc[j][e] += (xv[j][e] - mu) * rs * gv[j][e] + bv[j][e];
  }
#pragma unroll
  for (int j = 0; j < 4; ++j) *(floatx4*)(&red[w][j*256 + lane*4]) = acc[j];
  __syncthreads();
  const int p = tid * 4;
  floatx4 s0 = *(const floatx4*)(&red[0][p]);
  floatx4 s1 = *(const floatx4*)(&red[1][p]);
  floatx4 s2v = *(const floatx4*)(&red[2][p]);
  floatx4 s3 = *(const floatx4*)(&red[3][p]);
  *(floatx4*)(part + (size_t)blk*1024 + p) = s0 + s1 + s2v + s3;
}

// ---------------- K2a: reduce partials -> tile_repr; convert W1/W2 to bf16 ----------------
__global__ __launch_bounds__(256) void wk_reduce(const float* __restrict__ part, float* __restrict__ trep,
    const float* __restrict__ W1, const float* __restrict__ W2,
    unsigned short* __restrict__ W1bf, unsigned short* __restrict__ W2bf){
  __shared__ float red[4][64];
  const int j = blockIdx.x, b = j >> 4, chunk = j & 15;
  const int t = threadIdx.x, po = t & 63, part4 = t >> 6;
  const int p = chunk*64 + po;
  float s = 0.f;
  for (int i = 0; i < 32; ++i) s += part[(size_t)(b*128 + part4*32 + i)*1024 + p];
  red[part4][po] = s;
  __syncthreads();
  if (t < 64) trep[b*1024 + chunk*64 + t] = red[0][t] + red[1][t] + red[2][t] + red[3][t];
  for (int i = j*256 + t; i < 128*320; i += 64*256) W1bf[i] = f2bf(W1[i]);
  for (int i = j*256 + t; i < 64*128;  i += 64*256) W2bf[i] = f2bf(W2[i]);
}

// ---------------- K2b: routing (q/k linears, l2norm, scores, stable top-4) ----------------
__global__ __launch_bounds__(256) void wk_route(const float* __restrict__ trep,
    const float* __restrict__ Wq, const float* __restrict__ bq,
    const float* __restrict__ Wk, const float* __restrict__ bk, int* __restrict__ routes){
  __shared__ float tr[4096];
  __shared__ float qn[4096], kn[4096];
  __shared__ float redq[64][4], redk[64][4];
  const int t = threadIdx.x;
  for (int i = t; i < 4096; i += 256) tr[i] = trep[i] * (1.0f/4096.0f);
  __syncthreads();
  const int pair = t >> 2, part = t & 3;
  const float* trp = tr + pair*64;
  float qv[16], kv[16];
  float sq = 0.f, sk = 0.f;
  for (int dd = 0; dd < 16; ++dd){
    const int d = part*16 + dd;
    float aq = bq[d], ak = bk[d];
    const float* wqr = Wq + d*64;
    const float* wkr = Wk + d*64;
    for (int d2 = 0; d2 < 64; ++d2){ float v = trp[d2]; aq += wqr[d2]*v; ak += wkr[d2]*v; }
    qv[dd] = aq; kv[dd] = ak; sq += aq*aq; sk += ak*ak;
  }
  redq[pair][part] = sq; redk[pair][part] = sk;
  __syncthreads();
  const float nq = sqrtf(redq[pair][0]+redq[pair][1]+redq[pair][2]+redq[pair][3]);
  const float nk = sqrtf(redk[pair][0]+redk[pair][1]+redk[pair][2]+redk[pair][3]);
  const float iq = 1.0f / fmaxf(nq, 1e-12f), ik = 1.0f / fmaxf(nk, 1e-12f);
  for (int dd = 0; dd < 16; ++dd){
    qn[pair*64 + part*16 + dd] = qv[dd]*iq;
    kn[pair*64 + part*16 + dd] = kv[dd]*ik;
  }
  __syncthreads();
  if (t < 64){
    const int b = t >> 4, tt = t & 15;
    const float* qp = qn + t*64;
    float sc[16];
    for (int u = 0; u < 16; ++u){
      const float* kp = kn + (b*16 + u)*64;
      float s = 0.f;
      for (int d2 = 0; d2 < 64; ++d2) s += qp[d2]*kp[d2];
      sc[u] = s;
    }
    sc[tt] = -3.0e38f;
    for (int kk = 0; kk < 4; ++kk){
      float best = -3.4e38f; int bi = 0;
      for (int u = 0; u < 16; ++u) if (sc[u] > best){ best = sc[u]; bi = u; }
      routes[t*4 + kk] = bi;
      sc[bi] = -3.4e38f;
    }
  }
}

// ---------------- K3: fused LN + wormhole-MLP + residual (v2) ----------------
// 1024 blocks x 256 thr (4 waves). Per block: 16 rows, 4 quads of 4 rows.
// Wave w: W1 m-slice {2w,2w+1} in registers; LN + GEMM2 + store for quad-row w.
// LDS 40KB: xn[4][2048B] | Hb[4][4096B] | W2s[64][256B]  -> 2 blocks/CU.
#define MFMA16(accv, av, bbv) accv = __builtin_amdgcn_mfma_f32_16x16x32_bf16(av, bbv, accv, 0, 0, 0)

__global__ __launch_bounds__(256, 2) void wk_main(const float* __restrict__ x,
    const float* __restrict__ gm, const float* __restrict__ bt,
    const float* __restrict__ b1, const float* __restrict__ b2p,
    const unsigned short* __restrict__ W1bf, const unsigned short* __restrict__ W2bf,
    const int* __restrict__ routes, float* __restrict__ out){
  __shared__ char sm[40960];
  const int tid = threadIdx.x, w = tid >> 6, lane = tid & 63;
  const int c = lane & 15, g = lane >> 4;
  char* xnb = sm;            // [row r][2048B], XOR-swizzled by tile
  char* Hb  = sm + 8192;     // [row r][4096B]: [tile c][dim*2], XOR (c&7)<<4
  char* W2s = sm + 24576;    // [64 rows][256B], XOR (row&7)<<4
  // stage W2 swizzled
#pragma unroll
  for (int q = 0; q < 4; ++q){
    const int cid = tid*4 + q, row = cid >> 4, k16 = cid & 15;
    *(int4*)(W2s + row*256 + ((k16*16) ^ ((row & 7) << 4))) = *(const int4*)(W2bf + row*128 + k16*8);
  }
  // W1 m-slice -> registers: lane (c,g) holds W1[(2w+mi)*16+c][kk*32+g*8+e]
  bf16x8 w1f[2][10];
#pragma unroll
  for (int mi = 0; mi < 2; ++mi)
#pragma unroll
    for (int kk = 0; kk < 10; ++kk)
      w1f[mi][kk] = *(const bf16x8*)(W1bf + ((2*w + mi)*16 + c)*320 + kk*32 + g*8);
  floatx4 gvv[4], bvv[4];
#pragma unroll
  for (int j = 0; j < 4; ++j){
    gvv[j] = *(const floatx4*)(gm + j*256 + lane*4);
    bvv[j] = *(const floatx4*)(bt + j*256 + lane*4);
  }
  floatx4 b1v[2];
#pragma unroll
  for (int mi = 0; mi < 2; ++mi) b1v[mi] = *(const floatx4*)(b1 + (2*w + mi)*16 + g*4);
  float b2v[4];
#pragma unroll
  for (int nn = 0; nn < 4; ++nn) b2v[nn] = b2p[nn*16 + c];
  const int bbat = blockIdx.x >> 8;
  const int4 rt4 = *(const int4*)(routes + (bbat*16 + c)*4);
  const int rts[5] = {c, rt4.x, rt4.y, rt4.z, rt4.w};
  const int swc = (c & 7) << 4;
  const int g16 = g * 16;

#pragma unroll 1
  for (int q = 0; q < 4; ++q){
    const int row = blockIdx.x*16 + q*4 + w;
    // ---- LN for this wave's row (coalesced float4), keep x in regs for residual
    const float* xr = x + (size_t)row * 1024;
    floatx4 xv[4];
#pragma unroll
    for (int j = 0; j < 4; ++j) xv[j] = *(const floatx4*)(xr + j*256 + lane*4);
    float s = 0.f, s2 = 0.f;
#pragma unroll
    for (int j = 0; j < 4; ++j)
#pragma unroll
      for (int e = 0; e < 4; ++e){ float v = xv[j][e]; s += v; s2 += v*v; }
    s = wred64(s); s2 = wred64(s2);
    const float mu = s * (1.0f/1024.0f);
    const float rs = rsqrtf(s2 * (1.0f/1024.0f) - mu*mu + 1e-5f);
#pragma unroll
    for (int j = 0; j < 4; ++j){
      floatx4 xn = (xv[j] - mu) * rs * gvv[j] + bvv[j];
      uint2 pv; pv.x = pk2(xn[0], xn[1]); pv.y = pk2(xn[2], xn[3]);
      const int o = j*512 + lane*8;
      *(uint2*)(xnb + w*2048 + (o ^ (((o >> 7) & 7) << 4))) = pv;
    }
    __syncthreads();
    // ---- GEMM1: H[m-slice][tile c] for 4 quad-rows, W1 from regs, xn from LDS
    floatx4 acc[4][2];
#pragma unroll
    for (int r = 0; r < 4; ++r)
#pragma unroll
      for (int mi = 0; mi < 2; ++mi){ acc[r][mi][0]=0.f; acc[r][mi][1]=0.f; acc[r][mi][2]=0.f; acc[r][mi][3]=0.f; }
#pragma unroll
    for (int kk = 0; kk < 10; ++kk){
      const int s_ = rts[kk >> 1];
      const int baddr = (s_*128 + (kk & 1)*64 + g16) ^ ((s_ & 7) << 4);
      bf16x8 bfr[4];
#pragma unroll
      for (int r = 0; r < 4; ++r) bfr[r] = *(const bf16x8*)(xnb + r*2048 + baddr);
#pragma unroll
      for (int r = 0; r < 4; ++r)
#pragma unroll
        for (int mi = 0; mi < 2; ++mi)
          MFMA16(acc[r][mi], w1f[mi][kk], bfr[r]);
    }
    // ---- bias + GELU -> Hb (bf16)
#pragma unroll
    for (int r = 0; r < 4; ++r)
#pragma unroll
      for (int mi = 0; mi < 2; ++mi){
        floatx4 z = acc[r][mi] + b1v[mi];
        uint2 pv; pv.x = pk2(gelu_f(z[0]), gelu_f(z[1])); pv.y = pk2(gelu_f(z[2]), gelu_f(z[3]));
        *(uint2*)(Hb + r*4096 + c*256 + ((((2*w + mi)*32) + g*8) ^ swc)) = pv;
      }
    __syncthreads();
    // ---- GEMM2 for this wave's row (Hb[w] + W2s)
    floatx4 a2c[4];
#pragma unroll
    for (int n = 0; n < 4; ++n){ a2c[n][0]=0.f; a2c[n][1]=0.f; a2c[n][2]=0.f; a2c[n][3]=0.f; }
#pragma unroll
    for (int k2 = 0; k2 < 4; ++k2){
      const bf16x8 a2 = *(const bf16x8*)(Hb + w*4096 + c*256 + (((k2*64) + g16) ^ swc));
#pragma unroll
      for (int n = 0; n < 4; ++n){
        const bf16x8 b2f = *(const bf16x8*)(W2s + (n*16 + c)*256 + (((k2*64) + g16) ^ swc));
        MFMA16(a2c[n], a2, b2f);
      }
    }
    // ---- O -> LDS (overlay Hb[w], wave-private, DS in-order) -> float4 +residual store
    float* Ob = (float*)(Hb + w*4096);
#pragma unroll
    for (int n = 0; n < 4; ++n)
#pragma unroll
      for (int reg = 0; reg < 4; ++reg)
        Ob[(g*4 + reg)*64 + n*16 + c] = a2c[n][reg] + b2v[n];
    float* op = out + (size_t)row * 1024;
#pragma unroll
    for (int j = 0; j < 4; ++j){
      const floatx4 ov = *(const floatx4*)(Ob + j*256 + lane*4);
      *(floatx4*)(op + j*256 + lane*4) = ov + xv[j];
    }
    __syncthreads();
  }
}

extern "C" void kernel_launch(void* const* d_in, const int* in_sizes, int n_in,
                              void* d_out, int out_size, void* d_ws, size_t ws_size,
                              hipStream_t stream){
  const float* x  = (const float*)d_in[0];
  const float* gm = (const float*)d_in[1];
  const float* bt = (const float*)d_in[2];
  const float* Wq = (const float*)d_in[3];
  const float* bq = (const float*)d_in[4];
  const float* Wk = (const float*)d_in[5];
  const float* bk = (const float*)d_in[6];
  const float* W1 = (const float*)d_in[7];
  const float* b1 = (const float*)d_in[8];
  const float* W2 = (const float*)d_in[9];
  const float* b2 = (const float*)d_in[10];
  float* out = (float*)d_out;
  char* ws = (char*)d_ws;
  float* part = (float*)ws;                         // 512*1024 f32 = 2MB
  float* trep = part + 512*1024;                    // 4096 f32
  int*   routes = (int*)(trep + 4096);              // 256 i32
  unsigned short* W1bf = (unsigned short*)(ws + 2114560);  // 40960 bf16 (linear)
  unsigned short* W2bf = (unsigned short*)(ws + 2196480);  // 8192 bf16 (linear)

  wk_ln_part<<<512, 256, 0, stream>>>(x, gm, bt, part);
  wk_reduce<<<64, 256, 0, stream>>>(part, trep, W1, W2, W1bf, W2bf);
  wk_route<<<1, 256, 0, stream>>>(trep, Wq, bq, Wk, bk, routes);
  wk_main<<<1024, 256, 0, stream>>>(x, gm, bt, b1, b2, W1bf, W2bf, routes, out);
}

// Round 3
// 97.713 us; speedup vs baseline: 2.4932x; 1.4567x over previous
//
#include <hip/hip_runtime.h>
#include <hip/hip_bf16.h>

// Problem constants: B=4, S=4096, D=1024, T=16, TD=64, K=4
typedef float floatx4 __attribute__((ext_vector_type(4)));
typedef __bf16 bf16x8 __attribute__((ext_vector_type(8)));

__device__ __forceinline__ unsigned short f2bf(float f){
  unsigned u = __builtin_bit_cast(unsigned, f);
  u += 0x7fffu + ((u >> 16) & 1u);
  return (unsigned short)(u >> 16);
}
__device__ __forceinline__ unsigned pk2(float a, float b){
  return (unsigned)f2bf(a) | ((unsigned)f2bf(b) << 16);
}
__device__ __forceinline__ float wred64(float v){
  v += __shfl_xor(v, 32); v += __shfl_xor(v, 16); v += __shfl_xor(v, 8);
  v += __shfl_xor(v, 4);  v += __shfl_xor(v, 2);  v += __shfl_xor(v, 1);
  return v;
}
// tanh-form GELU via hardware exp2/rcp (|err| vs exact-erf < 1e-3, threshold 0.142)
__device__ __forceinline__ float gelu_f(float v){
  float u = v * v;
  float y = v * __builtin_fmaf(u, 0.0356774081f, 0.7978845608f);
  float a = __builtin_fabsf(y);
  float t = __builtin_amdgcn_exp2f(-2.8853900818f * a);   // e^{-2|y|}
  float th = (1.0f - t) * __builtin_amdgcn_rcpf(1.0f + t);
  return 0.5f * (v + __builtin_fabsf(v) * th);
}

// ---------------- K1: LN + per-block tile-sum partials (deterministic) ----------------
__global__ __launch_bounds__(256) void wk_ln_part(const float* __restrict__ x,
    const float* __restrict__ gm, const float* __restrict__ bt, float* __restrict__ part){
  __shared__ float red[4][1024];
  const int tid = threadIdx.x, w = tid >> 6, lane = tid & 63;
  const int blk = blockIdx.x;
  floatx4 gv[4], bv[4];
#pragma unroll
  for (int j = 0; j < 4; ++j){
    gv[j] = *(const floatx4*)(gm + j*256 + lane*4);
    bv[j] = *(const floatx4*)(bt + j*256 + lane*4);
  }
  floatx4 acc[4];
#pragma unroll
  for (int j = 0; j < 4; ++j){ acc[j][0]=0.f; acc[j][1]=0.f; acc[j][2]=0.f; acc[j][3]=0.f; }
  const int row0 = blk*32 + w*8;
#pragma unroll 2
  for (int r = 0; r < 8; ++r){
    const float* xr = x + (size_t)(row0 + r) * 1024;
    floatx4 xv[4];
#pragma unroll
    for (int j = 0; j < 4; ++j) xv[j] = *(const floatx4*)(xr + j*256 + lane*4);
    float s = 0.f, s2 = 0.f;
#pragma unroll
    for (int j = 0; j < 4; ++j)
#pragma unroll
      for (int e = 0; e < 4; ++e){ float v = xv[j][e]; s += v; s2 += v*v; }
    s = wred64(s); s2 = wred64(s2);
    const float mu = s * (1.0f/1024.0f);
    const float rs = rsqrtf(s2 * (1.0f/1024.0f) - mu*mu + 1e-5f);
#pragma unroll
    for (int j = 0; j < 4; ++j)
#pragma unroll
      for (int e = 0; e < 4; ++e)
        acc[j][e] += (xv[j][e] - mu) * rs * gv[j][e] + bv[j][e];
  }
#pragma unroll
  for (int j = 0; j < 4; ++j) *(floatx4*)(&red[w][j*256 + lane*4]) = acc[j];
  __syncthreads();
  const int p = tid * 4;
  floatx4 s0 = *(const floatx4*)(&red[0][p]);
  floatx4 s1 = *(const floatx4*)(&red[1][p]);
  floatx4 s2v = *(const floatx4*)(&red[2][p]);
  floatx4 s3 = *(const floatx4*)(&red[3][p]);
  *(floatx4*)(part + (size_t)blk*1024 + p) = s0 + s1 + s2v + s3;
}

// ---------------- K2a: reduce partials -> tile_repr; convert W1/W2 to bf16 ----------------
__global__ __launch_bounds__(256) void wk_reduce(const float* __restrict__ part, float* __restrict__ trep,
    const float* __restrict__ W1, const float* __restrict__ W2,
    unsigned short* __restrict__ W1bf, unsigned short* __restrict__ W2bf){
  __shared__ float red[4][64];
  const int j = blockIdx.x, b = j >> 4, chunk = j & 15;
  const int t = threadIdx.x, po = t & 63, part4 = t >> 6;
  const int p = chunk*64 + po;
  float s = 0.f;
  for (int i = 0; i < 32; ++i) s += part[(size_t)(b*128 + part4*32 + i)*1024 + p];
  red[part4][po] = s;
  __syncthreads();
  if (t < 64) trep[b*1024 + chunk*64 + t] = red[0][t] + red[1][t] + red[2][t] + red[3][t];
  for (int i = j*256 + t; i < 128*320; i += 64*256) W1bf[i] = f2bf(W1[i]);
  for (int i = j*256 + t; i < 64*128;  i += 64*256) W2bf[i] = f2bf(W2[i]);
}

// ---------------- K2b: routing v2 (scalar-path weights, wave=dim-slice, lane=pair) ------
// q = l2norm(trep_mean @ Wq^T + bq), k likewise; scores = q k^T; diag masked; top-4.
// fp32 with IDENTICAL summation order to v1 (which validated) -> identical routes.
__global__ __launch_bounds__(256) void wk_route(const float* __restrict__ trep,
    const float* __restrict__ Wq, const float* __restrict__ bq,
    const float* __restrict__ Wk, const float* __restrict__ bk, int* __restrict__ routes){
  __shared__ float tr[4096];          // swizzled: word = pair*64 + (jw ^ ((pair&7)<<2))
  __shared__ float qnt[4096], knt[4096];  // transposed: [d][pair]
  __shared__ float redq[4][64], redk[4][64];
  __shared__ float scs[1024];         // [pair][u]
  const int t = threadIdx.x, w = t >> 6, lane = t & 63;
  // stage tile means (swizzled, conflict-free: whole wave writes one row)
  for (int i = t; i < 4096; i += 256){
    const int row = i >> 6, jw = i & 63;
    tr[row*64 + (jw ^ ((row & 7) << 2))] = trep[i] * (1.0f/4096.0f);
  }
  __syncthreads();
  // lane = pair (b*16+tile); wave w owns dims [16w,16w+16)
  float trv[64];
  {
    const int sw = (lane & 7) << 2;
#pragma unroll
    for (int j = 0; j < 16; ++j){
      const floatx4 v = *(const floatx4*)(&tr[lane*64 + ((j*4) ^ sw)]);
      trv[j*4+0]=v[0]; trv[j*4+1]=v[1]; trv[j*4+2]=v[2]; trv[j*4+3]=v[3];
    }
  }
  float qv[16], kv[16], sq = 0.f, sk = 0.f;
#pragma unroll 4
  for (int dd = 0; dd < 16; ++dd){
    const int d = __builtin_amdgcn_readfirstlane(w*16 + dd);
    const float* wqr = Wq + d*64;
    const float* wkr = Wk + d*64;
    float aq = bq[d], ak = bk[d];
#pragma unroll
    for (int j = 0; j < 64; ++j){
      aq = __builtin_fmaf(wqr[j], trv[j], aq);
      ak = __builtin_fmaf(wkr[j], trv[j], ak);
    }
    qv[dd] = aq; kv[dd] = ak; sq += aq*aq; sk += ak*ak;
  }
  redq[w][lane] = sq; redk[w][lane] = sk;
  __syncthreads();
  const float nq = sqrtf(redq[0][lane]+redq[1][lane]+redq[2][lane]+redq[3][lane]);
  const float nk = sqrtf(redk[0][lane]+redk[1][lane]+redk[2][lane]+redk[3][lane]);
  const float iq = 1.0f / fmaxf(nq, 1e-12f), ik = 1.0f / fmaxf(nk, 1e-12f);
#pragma unroll
  for (int dd = 0; dd < 16; ++dd){
    qnt[(w*16 + dd)*64 + lane] = qv[dd]*iq;   // transposed -> conflict-free (lane contiguous)
    knt[(w*16 + dd)*64 + lane] = kv[dd]*ik;
  }
  __syncthreads();
  // scores: thread t -> 4 scores (same b,tt; uu = uu0..uu0+3)
  {
    const int sidx = t*4, b = sidx >> 8, tt = (sidx >> 4) & 15, uu0 = sidx & 15;
    const int qp = b*16 + tt;
    float qrow[64];
#pragma unroll
    for (int dd = 0; dd < 64; ++dd) qrow[dd] = qnt[dd*64 + qp];
#pragma unroll
    for (int e = 0; e < 4; ++e){
      const int kp = b*16 + uu0 + e;
      float s = 0.f;
#pragma unroll
      for (int dd = 0; dd < 64; ++dd) s = __builtin_fmaf(qrow[dd], knt[dd*64 + kp], s);
      scs[qp*16 + uu0 + e] = s;
    }
  }
  __syncthreads();
  if (t < 64){
    const int tt = t & 15;
    float sc[16];
#pragma unroll
    for (int u = 0; u < 16; ++u) sc[u] = scs[t*16 + u];
    sc[tt] = -3.0e38f;
    for (int kk = 0; kk < 4; ++kk){
      float best = -3.4e38f; int bi = 0;
#pragma unroll
      for (int u = 0; u < 16; ++u) if (sc[u] > best){ best = sc[u]; bi = u; }
      routes[t*4 + kk] = bi;
      sc[bi] = -3.4e38f;
    }
  }
}

// ---------------- K3: fused LN + wormhole-MLP + residual (v2) ----------------
// 1024 blocks x 256 thr (4 waves). Per block: 16 rows, 4 quads of 4 rows.
// Wave w: W1 m-slice {2w,2w+1} in registers; LN + GEMM2 + store for quad-row w.
// LDS 40KB: xn[4][2048B] | Hb[4][4096B] | W2s[64][256B]  -> 2 blocks/CU.
#define MFMA16(accv, av, bbv) accv = __builtin_amdgcn_mfma_f32_16x16x32_bf16(av, bbv, accv, 0, 0, 0)

__global__ __launch_bounds__(256, 2) void wk_main(const float* __restrict__ x,
    const float* __restrict__ gm, const float* __restrict__ bt,
    const float* __restrict__ b1, const float* __restrict__ b2p,
    const unsigned short* __restrict__ W1bf, const unsigned short* __restrict__ W2bf,
    const int* __restrict__ routes, float* __restrict__ out){
  __shared__ char sm[40960];
  const int tid = threadIdx.x, w = tid >> 6, lane = tid & 63;
  const int c = lane & 15, g = lane >> 4;
  char* xnb = sm;            // [row r][2048B], XOR-swizzled by tile
  char* Hb  = sm + 8192;     // [row r][4096B]: [tile c][dim*2], XOR (c&7)<<4
  char* W2s = sm + 24576;    // [64 rows][256B], XOR (row&7)<<4
  // stage W2 swizzled
#pragma unroll
  for (int q = 0; q < 4; ++q){
    const int cid = tid*4 + q, row = cid >> 4, k16 = cid & 15;
    *(int4*)(W2s + row*256 + ((k16*16) ^ ((row & 7) << 4))) = *(const int4*)(W2bf + row*128 + k16*8);
  }
  // W1 m-slice -> registers: lane (c,g) holds W1[(2w+mi)*16+c][kk*32+g*8+e]
  bf16x8 w1f[2][10];
#pragma unroll
  for (int mi = 0; mi < 2; ++mi)
#pragma unroll
    for (int kk = 0; kk < 10; ++kk)
      w1f[mi][kk] = *(const bf16x8*)(W1bf + ((2*w + mi)*16 + c)*320 + kk*32 + g*8);
  floatx4 gvv[4], bvv[4];
#pragma unroll
  for (int j = 0; j < 4; ++j){
    gvv[j] = *(const floatx4*)(gm + j*256 + lane*4);
    bvv[j] = *(const floatx4*)(bt + j*256 + lane*4);
  }
  floatx4 b1v[2];
#pragma unroll
  for (int mi = 0; mi < 2; ++mi) b1v[mi] = *(const floatx4*)(b1 + (2*w + mi)*16 + g*4);
  float b2v[4];
#pragma unroll
  for (int nn = 0; nn < 4; ++nn) b2v[nn] = b2p[nn*16 + c];
  const int bbat = blockIdx.x >> 8;
  const int4 rt4 = *(const int4*)(routes + (bbat*16 + c)*4);
  const int rts[5] = {c, rt4.x, rt4.y, rt4.z, rt4.w};
  const int swc = (c & 7) << 4;
  const int g16 = g * 16;

#pragma unroll 1
  for (int q = 0; q < 4; ++q){
    const int row = blockIdx.x*16 + q*4 + w;
    // ---- LN for this wave's row (coalesced float4), keep x in regs for residual
    const float* xr = x + (size_t)row * 1024;
    floatx4 xv[4];
#pragma unroll
    for (int j = 0; j < 4; ++j) xv[j] = *(const floatx4*)(xr + j*256 + lane*4);
    float s = 0.f, s2 = 0.f;
#pragma unroll
    for (int j = 0; j < 4; ++j)
#pragma unroll
      for (int e = 0; e < 4; ++e){ float v = xv[j][e]; s += v; s2 += v*v; }
    s = wred64(s); s2 = wred64(s2);
    const float mu = s * (1.0f/1024.0f);
    const float rs = rsqrtf(s2 * (1.0f/1024.0f) - mu*mu + 1e-5f);
#pragma unroll
    for (int j = 0; j < 4; ++j){
      floatx4 xn = (xv[j] - mu) * rs * gvv[j] + bvv[j];
      uint2 pv; pv.x = pk2(xn[0], xn[1]); pv.y = pk2(xn[2], xn[3]);
      const int o = j*512 + lane*8;
      *(uint2*)(xnb + w*2048 + (o ^ (((o >> 7) & 7) << 4))) = pv;
    }
    __syncthreads();
    // ---- GEMM1: H[m-slice][tile c] for 4 quad-rows, W1 from regs, xn from LDS
    floatx4 acc[4][2];
#pragma unroll
    for (int r = 0; r < 4; ++r)
#pragma unroll
      for (int mi = 0; mi < 2; ++mi){ acc[r][mi][0]=0.f; acc[r][mi][1]=0.f; acc[r][mi][2]=0.f; acc[r][mi][3]=0.f; }
#pragma unroll
    for (int kk = 0; kk < 10; ++kk){
      const int s_ = rts[kk >> 1];
      const int baddr = (s_*128 + (kk & 1)*64 + g16) ^ ((s_ & 7) << 4);
      bf16x8 bfr[4];
#pragma unroll
      for (int r = 0; r < 4; ++r) bfr[r] = *(const bf16x8*)(xnb + r*2048 + baddr);
#pragma unroll
      for (int r = 0; r < 4; ++r)
#pragma unroll
        for (int mi = 0; mi < 2; ++mi)
          MFMA16(acc[r][mi], w1f[mi][kk], bfr[r]);
    }
    // ---- bias + GELU -> Hb (bf16)
#pragma unroll
    for (int r = 0; r < 4; ++r)
#pragma unroll
      for (int mi = 0; mi < 2; ++mi){
        floatx4 z = acc[r][mi] + b1v[mi];
        uint2 pv; pv.x = pk2(gelu_f(z[0]), gelu_f(z[1])); pv.y = pk2(gelu_f(z[2]), gelu_f(z[3]));
        *(uint2*)(Hb + r*4096 + c*256 + ((((2*w + mi)*32) + g*8) ^ swc)) = pv;
      }
    __syncthreads();
    // ---- GEMM2 for this wave's row (Hb[w] + W2s)
    floatx4 a2c[4];
#pragma unroll
    for (int n = 0; n < 4; ++n){ a2c[n][0]=0.f; a2c[n][1]=0.f; a2c[n][2]=0.f; a2c[n][3]=0.f; }
#pragma unroll
    for (int k2 = 0; k2 < 4; ++k2){
      const bf16x8 a2 = *(const bf16x8*)(Hb + w*4096 + c*256 + (((k2*64) + g16) ^ swc));
#pragma unroll
      for (int n = 0; n < 4; ++n){
        const bf16x8 b2f = *(const bf16x8*)(W2s + (n*16 + c)*256 + (((k2*64) + g16) ^ swc));
        MFMA16(a2c[n], a2, b2f);
      }
    }
    // ---- O -> LDS (overlay Hb[w], wave-private, DS in-order) -> float4 +residual store
    float* Ob = (float*)(Hb + w*4096);
#pragma unroll
    for (int n = 0; n < 4; ++n)
#pragma unroll
      for (int reg = 0; reg < 4; ++reg)
        Ob[(g*4 + reg)*64 + n*16 + c] = a2c[n][reg] + b2v[n];
    float* op = out + (size_t)row * 1024;
#pragma unroll
    for (int j = 0; j < 4; ++j){
      const floatx4 ov = *(const floatx4*)(Ob + j*256 + lane*4);
      *(floatx4*)(op + j*256 + lane*4) = ov + xv[j];
    }
    __syncthreads();
  }
}

extern "C" void kernel_launch(void* const* d_in, const int* in_sizes, int n_in,
                              void* d_out, int out_size, void* d_ws, size_t ws_size,
                              hipStream_t stream){
  const float* x  = (const float*)d_in[0];
  const float* gm = (const float*)d_in[1];
  const float* bt = (const float*)d_in[2];
  const float* Wq = (const float*)d_in[3];
  const float* bq = (const float*)d_in[4];
  const float* Wk = (const float*)d_in[5];
  const float* bk = (const float*)d_in[6];
  const float* W1 = (const float*)d_in[7];
  const float* b1 = (const float*)d_in[8];
  const float* W2 = (const float*)d_in[9];
  const float* b2 = (const float*)d_in[10];
  float* out = (float*)d_out;
  char* ws = (char*)d_ws;
  float* part = (float*)ws;                         // 512*1024 f32 = 2MB
  float* trep = part + 512*1024;                    // 4096 f32
  int*   routes = (int*)(trep + 4096);              // 256 i32
  unsigned short* W1bf = (unsigned short*)(ws + 2114560);  // 40960 bf16 (linear)
  unsigned short* W2bf = (unsigned short*)(ws + 2196480);  // 8192 bf16 (linear)

  wk_ln_part<<<512, 256, 0, stream>>>(x, gm, bt, part);
  wk_reduce<<<64, 256, 0, stream>>>(part, trep, W1, W2, W1bf, W2bf);
  wk_route<<<1, 256, 0, stream>>>(trep, Wq, bq, Wk, bk, routes);
  wk_main<<<1024, 256, 0, stream>>>(x, gm, bt, b1, b2, W1bf, W2bf, routes, out);
}

// Round 6
// 96.696 us; speedup vs baseline: 2.5195x; 1.0105x over previous
//
#include <hip/hip_runtime.h>
#include <hip/hip_bf16.h>

// Problem constants: B=4, S=4096, D=1024, T=16, TD=64, K=4
typedef float floatx4 __attribute__((ext_vector_type(4)));
typedef __bf16 bf16x8 __attribute__((ext_vector_type(8)));

__device__ __forceinline__ unsigned short f2bf(float f){
  unsigned u = __builtin_bit_cast(unsigned, f);
  u += 0x7fffu + ((u >> 16) & 1u);
  return (unsigned short)(u >> 16);
}
__device__ __forceinline__ unsigned pk2(float a, float b){
  return (unsigned)f2bf(a) | ((unsigned)f2bf(b) << 16);
}
__device__ __forceinline__ float wred64(float v){
  v += __shfl_xor(v, 32); v += __shfl_xor(v, 16); v += __shfl_xor(v, 8);
  v += __shfl_xor(v, 4);  v += __shfl_xor(v, 2);  v += __shfl_xor(v, 1);
  return v;
}
// tanh-form GELU via hardware exp2/rcp (|err| vs exact-erf < 1e-3, threshold 0.142)
__device__ __forceinline__ float gelu_f(float v){
  float u = v * v;
  float y = v * __builtin_fmaf(u, 0.0356774081f, 0.7978845608f);
  float a = __builtin_fabsf(y);
  float t = __builtin_amdgcn_exp2f(-2.8853900818f * a);   // e^{-2|y|}
  float th = (1.0f - t) * __builtin_amdgcn_rcpf(1.0f + t);
  return 0.5f * (v + __builtin_fabsf(v) * th);
}

// ---------------- K1: LN + per-block tile-sum partials (deterministic) ----------------
__global__ __launch_bounds__(256) void wk_ln_part(const float* __restrict__ x,
    const float* __restrict__ gm, const float* __restrict__ bt, float* __restrict__ part){
  __shared__ float red[4][1024];
  const int tid = threadIdx.x, w = tid >> 6, lane = tid & 63;
  const int blk = blockIdx.x;
  floatx4 gv[4], bv[4];
#pragma unroll
  for (int j = 0; j < 4; ++j){
    gv[j] = *(const floatx4*)(gm + j*256 + lane*4);
    bv[j] = *(const floatx4*)(bt + j*256 + lane*4);
  }
  floatx4 acc[4];
#pragma unroll
  for (int j = 0; j < 4; ++j){ acc[j][0]=0.f; acc[j][1]=0.f; acc[j][2]=0.f; acc[j][3]=0.f; }
  const int row0 = blk*32 + w*8;
#pragma unroll 2
  for (int r = 0; r < 8; ++r){
    const float* xr = x + (size_t)(row0 + r) * 1024;
    floatx4 xv[4];
#pragma unroll
    for (int j = 0; j < 4; ++j) xv[j] = *(const floatx4*)(xr + j*256 + lane*4);
    float s = 0.f, s2 = 0.f;
#pragma unroll
    for (int j = 0; j < 4; ++j)
#pragma unroll
      for (int e = 0; e < 4; ++e){ float v = xv[j][e]; s += v; s2 += v*v; }
    s = wred64(s); s2 = wred64(s2);
    const float mu = s * (1.0f/1024.0f);
    const float rs = rsqrtf(s2 * (1.0f/1024.0f) - mu*mu + 1e-5f);
#pragma unroll
    for (int j = 0; j < 4; ++j)
#pragma unroll
      for (int e = 0; e < 4; ++e)
        acc[j][e] += (xv[j][e] - mu) * rs * gv[j][e] + bv[j][e];
  }
#pragma unroll
  for (int j = 0; j < 4; ++j) *(floatx4*)(&red[w][j*256 + lane*4]) = acc[j];
  __syncthreads();
  const int p = tid * 4;
  floatx4 s0 = *(const floatx4*)(&red[0][p]);
  floatx4 s1 = *(const floatx4*)(&red[1][p]);
  floatx4 s2v = *(const floatx4*)(&red[2][p]);
  floatx4 s3 = *(const floatx4*)(&red[3][p]);
  *(floatx4*)(part + (size_t)blk*1024 + p) = s0 + s1 + s2v + s3;
}

// ---------------- K2a: reduce partials -> tile_repr; convert W1/W2 to bf16 ----------------
__global__ __launch_bounds__(256) void wk_reduce(const float* __restrict__ part, float* __restrict__ trep,
    const float* __restrict__ W1, const float* __restrict__ W2,
    unsigned short* __restrict__ W1bf, unsigned short* __restrict__ W2bf){
  __shared__ float red[4][64];
  const int j = blockIdx.x, b = j >> 4, chunk = j & 15;
  const int t = threadIdx.x, po = t & 63, part4 = t >> 6;
  const int p = chunk*64 + po;
  float s = 0.f;
  for (int i = 0; i < 32; ++i) s += part[(size_t)(b*128 + part4*32 + i)*1024 + p];
  red[part4][po] = s;
  __syncthreads();
  if (t < 64) trep[b*1024 + chunk*64 + t] = red[0][t] + red[1][t] + red[2][t] + red[3][t];
  for (int i = j*256 + t; i < 128*320; i += 64*256) W1bf[i] = f2bf(W1[i]);
  for (int i = j*256 + t; i < 64*128;  i += 64*256) W2bf[i] = f2bf(W2[i]);
}

// ---------------- K2b: routing v2 (scalar-path weights, wave=dim-slice, lane=pair) ------
__global__ __launch_bounds__(256) void wk_route(const float* __restrict__ trep,
    const float* __restrict__ Wq, const float* __restrict__ bq,
    const float* __restrict__ Wk, const float* __restrict__ bk, int* __restrict__ routes){
  __shared__ float tr[4096];          // swizzled: word = pair*64 + (jw ^ ((pair&7)<<2))
  __shared__ float qnt[4096], knt[4096];  // transposed: [d][pair]
  __shared__ float redq[4][64], redk[4][64];
  __shared__ float scs[1024];         // [pair][u]
  const int t = threadIdx.x, w = t >> 6, lane = t & 63;
  for (int i = t; i < 4096; i += 256){
    const int row = i >> 6, jw = i & 63;
    tr[row*64 + (jw ^ ((row & 7) << 2))] = trep[i] * (1.0f/4096.0f);
  }
  __syncthreads();
  float trv[64];
  {
    const int sw = (lane & 7) << 2;
#pragma unroll
    for (int j = 0; j < 16; ++j){
      const floatx4 v = *(const floatx4*)(&tr[lane*64 + ((j*4) ^ sw)]);
      trv[j*4+0]=v[0]; trv[j*4+1]=v[1]; trv[j*4+2]=v[2]; trv[j*4+3]=v[3];
    }
  }
  float qv[16], kv[16], sq = 0.f, sk = 0.f;
#pragma unroll 4
  for (int dd = 0; dd < 16; ++dd){
    const int d = __builtin_amdgcn_readfirstlane(w*16 + dd);
    const float* wqr = Wq + d*64;
    const float* wkr = Wk + d*64;
    float aq = bq[d], ak = bk[d];
#pragma unroll
    for (int j = 0; j < 64; ++j){
      aq = __builtin_fmaf(wqr[j], trv[j], aq);
      ak = __builtin_fmaf(wkr[j], trv[j], ak);
    }
    qv[dd] = aq; kv[dd] = ak; sq += aq*aq; sk += ak*ak;
  }
  redq[w][lane] = sq; redk[w][lane] = sk;
  __syncthreads();
  const float nq = sqrtf(redq[0][lane]+redq[1][lane]+redq[2][lane]+redq[3][lane]);
  const float nk = sqrtf(redk[0][lane]+redk[1][lane]+redk[2][lane]+redk[3][lane]);
  const float iq = 1.0f / fmaxf(nq, 1e-12f), ik = 1.0f / fmaxf(nk, 1e-12f);
#pragma unroll
  for (int dd = 0; dd < 16; ++dd){
    qnt[(w*16 + dd)*64 + lane] = qv[dd]*iq;
    knt[(w*16 + dd)*64 + lane] = kv[dd]*ik;
  }
  __syncthreads();
  {
    const int sidx = t*4, b = sidx >> 8, tt = (sidx >> 4) & 15, uu0 = sidx & 15;
    const int qp = b*16 + tt;
    float qrow[64];
#pragma unroll
    for (int dd = 0; dd < 64; ++dd) qrow[dd] = qnt[dd*64 + qp];
#pragma unroll
    for (int e = 0; e < 4; ++e){
      const int kp = b*16 + uu0 + e;
      float s = 0.f;
#pragma unroll
      for (int dd = 0; dd < 64; ++dd) s = __builtin_fmaf(qrow[dd], knt[dd*64 + kp], s);
      scs[qp*16 + uu0 + e] = s;
    }
  }
  __syncthreads();
  if (t < 64){
    const int tt = t & 15;
    float sc[16];
#pragma unroll
    for (int u = 0; u < 16; ++u) sc[u] = scs[t*16 + u];
    sc[tt] = -3.0e38f;
    for (int kk = 0; kk < 4; ++kk){
      float best = -3.4e38f; int bi = 0;
#pragma unroll
      for (int u = 0; u < 16; ++u) if (sc[u] > best){ best = sc[u]; bi = u; }
      routes[t*4 + kk] = bi;
      sc[bi] = -3.4e38f;
    }
  }
}

// ---------------- K3: fused LN + wormhole-MLP + residual (v5 = proven v2 + Ob swizzle) --
// 1024 blocks x 256 thr (4 waves). Per block: 16 rows, 4 quads of 4 rows.
// Wave w: W1 m-slice {2w,2w+1} in registers; LN + GEMM2 + store for quad-row w.
// LDS 40KB: xn[4][2048B] | Hb[4][4096B] | W2s[64][256B].
// NOTE: __launch_bounds__(256,2) — (256,4) build failed with out==0 (rounds 4/5);
// resources (128 VGPR, 40KB LDS) already admit 4 blocks/CU without the stronger bound.
#define MFMA16(accv, av, bbv) accv = __builtin_amdgcn_mfma_f32_16x16x32_bf16(av, bbv, accv, 0, 0, 0)

__global__ __launch_bounds__(256, 2) void wk_main(const float* __restrict__ x,
    const float* __restrict__ gm, const float* __restrict__ bt,
    const float* __restrict__ b1, const float* __restrict__ b2p,
    const unsigned short* __restrict__ W1bf, const unsigned short* __restrict__ W2bf,
    const int* __restrict__ routes, float* __restrict__ out){
  __shared__ char sm[40960];
  const int tid = threadIdx.x, w = tid >> 6, lane = tid & 63;
  const int c = lane & 15, g = lane >> 4;
  char* xnb = sm;            // [row r][2048B], XOR-swizzled by tile
  char* Hb  = sm + 8192;     // [row r][4096B]: [tile c][dim*2], XOR (c&7)<<4
  char* W2s = sm + 24576;    // [64 rows][256B], XOR (row&7)<<4
#pragma unroll
  for (int q = 0; q < 4; ++q){
    const int cid = tid*4 + q, row = cid >> 4, k16 = cid & 15;
    *(int4*)(W2s + row*256 + ((k16*16) ^ ((row & 7) << 4))) = *(const int4*)(W2bf + row*128 + k16*8);
  }
  // W1 m-slice -> registers: lane (c,g) holds W1[(2w+mi)*16+c][kk*32+g*8+e]
  bf16x8 w1f[2][10];
#pragma unroll
  for (int mi = 0; mi < 2; ++mi)
#pragma unroll
    for (int kk = 0; kk < 10; ++kk)
      w1f[mi][kk] = *(const bf16x8*)(W1bf + ((2*w + mi)*16 + c)*320 + kk*32 + g*8);
  floatx4 gvv[4], bvv[4];
#pragma unroll
  for (int j = 0; j < 4; ++j){
    gvv[j] = *(const floatx4*)(gm + j*256 + lane*4);
    bvv[j] = *(const floatx4*)(bt + j*256 + lane*4);
  }
  floatx4 b1v[2];
#pragma unroll
  for (int mi = 0; mi < 2; ++mi) b1v[mi] = *(const floatx4*)(b1 + (2*w + mi)*16 + g*4);
  float b2v[4];
#pragma unroll
  for (int nn = 0; nn < 4; ++nn) b2v[nn] = b2p[nn*16 + c];
  const int bbat = blockIdx.x >> 8;
  const int4 rt4 = *(const int4*)(routes + (bbat*16 + c)*4);
  const int rts[5] = {c, rt4.x, rt4.y, rt4.z, rt4.w};
  const int swc = (c & 7) << 4;
  const int g16 = g * 16;

#pragma unroll 1
  for (int q = 0; q < 4; ++q){
    const int row = blockIdx.x*16 + q*4 + w;
    // ---- LN for this wave's row (coalesced float4), keep x in regs for residual
    const float* xr = x + (size_t)row * 1024;
    floatx4 xv[4];
#pragma unroll
    for (int j = 0; j < 4; ++j) xv[j] = *(const floatx4*)(xr + j*256 + lane*4);
    float s = 0.f, s2 = 0.f;
#pragma unroll
    for (int j = 0; j < 4; ++j)
#pragma unroll
      for (int e = 0; e < 4; ++e){ float v = xv[j][e]; s += v; s2 += v*v; }
    s = wred64(s); s2 = wred64(s2);
    const float mu = s * (1.0f/1024.0f);
    const float rs = rsqrtf(s2 * (1.0f/1024.0f) - mu*mu + 1e-5f);
#pragma unroll
    for (int j = 0; j < 4; ++j){
      floatx4 xn = (xv[j] - mu) * rs * gvv[j] + bvv[j];
      uint2 pv; pv.x = pk2(xn[0], xn[1]); pv.y = pk2(xn[2], xn[3]);
      const int o = j*512 + lane*8;
      *(uint2*)(xnb + w*2048 + (o ^ (((o >> 7) & 7) << 4))) = pv;
    }
    __syncthreads();
    // ---- GEMM1: H[m-slice][tile c] for 4 quad-rows, W1 from regs, xn from LDS
    floatx4 acc[4][2];
#pragma unroll
    for (int r = 0; r < 4; ++r)
#pragma unroll
      for (int mi = 0; mi < 2; ++mi){ acc[r][mi][0]=0.f; acc[r][mi][1]=0.f; acc[r][mi][2]=0.f; acc[r][mi][3]=0.f; }
#pragma unroll
    for (int kk = 0; kk < 10; ++kk){
      const int s_ = rts[kk >> 1];
      const int baddr = (s_*128 + (kk & 1)*64 + g16) ^ ((s_ & 7) << 4);
      bf16x8 bfr[4];
#pragma unroll
      for (int r = 0; r < 4; ++r) bfr[r] = *(const bf16x8*)(xnb + r*2048 + baddr);
#pragma unroll
      for (int r = 0; r < 4; ++r)
#pragma unroll
        for (int mi = 0; mi < 2; ++mi)
          MFMA16(acc[r][mi], w1f[mi][kk], bfr[r]);
    }
    // ---- bias + GELU -> Hb (bf16)
#pragma unroll
    for (int r = 0; r < 4; ++r)
#pragma unroll
      for (int mi = 0; mi < 2; ++mi){
        floatx4 z = acc[r][mi] + b1v[mi];
        uint2 pv; pv.x = pk2(gelu_f(z[0]), gelu_f(z[1])); pv.y = pk2(gelu_f(z[2]), gelu_f(z[3]));
        *(uint2*)(Hb + r*4096 + c*256 + ((((2*w + mi)*32) + g*8) ^ swc)) = pv;
      }
    __syncthreads();
    // ---- GEMM2 for this wave's row (Hb[w] + W2s)
    floatx4 a2c[4];
#pragma unroll
    for (int n = 0; n < 4; ++n){ a2c[n][0]=0.f; a2c[n][1]=0.f; a2c[n][2]=0.f; a2c[n][3]=0.f; }
#pragma unroll
    for (int k2 = 0; k2 < 4; ++k2){
      const bf16x8 a2 = *(const bf16x8*)(Hb + w*4096 + c*256 + (((k2*64) + g16) ^ swc));
#pragma unroll
      for (int n = 0; n < 4; ++n){
        const bf16x8 b2f = *(const bf16x8*)(W2s + (n*16 + c)*256 + (((k2*64) + g16) ^ swc));
        MFMA16(a2c[n], a2, b2f);
      }
    }
    // ---- O -> LDS (overlay Hb[w], wave-private, XOR word idx by (orow&7)<<2) -> float4 store
    float* Ob = (float*)(Hb + w*4096);
#pragma unroll
    for (int n = 0; n < 4; ++n)
#pragma unroll
      for (int reg = 0; reg < 4; ++reg){
        const int orow = g*4 + reg;
        Ob[orow*64 + ((n*16 + c) ^ ((orow & 7) << 2))] = a2c[n][reg] + b2v[n];
      }
    float* op = out + (size_t)row * 1024;
#pragma unroll
    for (int j = 0; j < 4; ++j){
      const int orow = j*4 + g;
      const floatx4 ov = *(const floatx4*)(Ob + orow*64 + ((c*4) ^ ((orow & 7) << 2)));
      *(floatx4*)(op + j*256 + lane*4) = ov + xv[j];
    }
    __syncthreads();
  }
}

extern "C" void kernel_launch(void* const* d_in, const int* in_sizes, int n_in,
                              void* d_out, int out_size, void* d_ws, size_t ws_size,
                              hipStream_t stream){
  const float* x  = (const float*)d_in[0];
  const float* gm = (const float*)d_in[1];
  const float* bt = (const float*)d_in[2];
  const float* Wq = (const float*)d_in[3];
  const float* bq = (const float*)d_in[4];
  const float* Wk = (const float*)d_in[5];
  const float* bk = (const float*)d_in[6];
  const float* W1 = (const float*)d_in[7];
  const float* b1 = (const float*)d_in[8];
  const float* W2 = (const float*)d_in[9];
  const float* b2 = (const float*)d_in[10];
  float* out = (float*)d_out;
  char* ws = (char*)d_ws;
  float* part = (float*)ws;                         // 512*1024 f32 = 2MB
  float* trep = part + 512*1024;                    // 4096 f32
  int*   routes = (int*)(trep + 4096);              // 256 i32
  unsigned short* W1bf = (unsigned short*)(ws + 2114560);  // 40960 bf16 (linear)
  unsigned short* W2bf = (unsigned short*)(ws + 2196480);  // 8192 bf16 (linear)

  wk_ln_part<<<512, 256, 0, stream>>>(x, gm, bt, part);
  wk_reduce<<<64, 256, 0, stream>>>(part, trep, W1, W2, W1bf, W2bf);
  wk_route<<<1, 256, 0, stream>>>(trep, Wq, bq, Wk, bk, routes);
  wk_main<<<1024, 256, 0, stream>>>(x, gm, bt, b1, b2, W1bf, W2bf, routes, out);
}